// Round 3
// baseline (159.278 us; speedup 1.0000x reference)
//
#include <hip/hip_runtime.h>

#define D 256
#define LKEYS 128
#define NGROUP 1024

// ---------------------------------------------------------------------------
// prep: M[a][b] = sum_z Wq[a,z] * Wk[b,z]   (M = Wq @ Wk^T)
//       r[b]    = sum_z bq[z]   * Wk[b,z]   (r = bq @ Wk^T)
// bk dropped: <bk, qz[i]> is per-query constant -> softmax-invariant.
// ---------------------------------------------------------------------------
__global__ __launch_bounds__(256) void prep_kernel(
    const float* __restrict__ Wq, const float* __restrict__ Wk,
    const float* __restrict__ bq, float* __restrict__ Mmat,
    float* __restrict__ rvec)
{
    __shared__ float wq_s[32][65];
    __shared__ float wk_s[32][65];
    __shared__ float bq_s[64];
    const int t  = threadIdx.x;
    const int a0 = (int)(blockIdx.x >> 3) * 32;
    const int b0 = (int)(blockIdx.x & 7) * 32;
    const int ai = t >> 4;
    const int bj = t & 15;
    float acc00 = 0.f, acc01 = 0.f, acc10 = 0.f, acc11 = 0.f;
    float racc = 0.f;
    for (int z0 = 0; z0 < D; z0 += 64) {
        __syncthreads();
        #pragma unroll
        for (int i = 0; i < 2; ++i) {
            const int f4i = t + 256 * i;
            const int row = f4i >> 4;
            const int c   = (f4i & 15) * 4;
            float4 aa = *(const float4*)&Wq[(size_t)(a0 + row) * D + z0 + c];
            wq_s[row][c] = aa.x; wq_s[row][c+1] = aa.y; wq_s[row][c+2] = aa.z; wq_s[row][c+3] = aa.w;
            float4 bb = *(const float4*)&Wk[(size_t)(b0 + row) * D + z0 + c];
            wk_s[row][c] = bb.x; wk_s[row][c+1] = bb.y; wk_s[row][c+2] = bb.z; wk_s[row][c+3] = bb.w;
        }
        if (t < 64) bq_s[t] = bq[z0 + t];
        __syncthreads();
        #pragma unroll 8
        for (int z = 0; z < 64; ++z) {
            const float wq0 = wq_s[ai][z];
            const float wq1 = wq_s[ai + 16][z];
            const float wk0 = wk_s[bj][z];
            const float wk1 = wk_s[bj + 16][z];
            acc00 += wq0 * wk0; acc01 += wq0 * wk1;
            acc10 += wq1 * wk0; acc11 += wq1 * wk1;
        }
        if (a0 == 0 && t < 32) {
            #pragma unroll 8
            for (int z = 0; z < 64; ++z) racc += bq_s[z] * wk_s[t][z];
        }
    }
    Mmat[(size_t)(a0 + ai)      * D + b0 + bj]      = acc00;
    Mmat[(size_t)(a0 + ai)      * D + b0 + bj + 16] = acc01;
    Mmat[(size_t)(a0 + ai + 16) * D + b0 + bj]      = acc10;
    Mmat[(size_t)(a0 + ai + 16) * D + b0 + bj + 16] = acc11;
    if (a0 == 0 && t < 32) rvec[b0 + t] = racc;
}

// ---------------------------------------------------------------------------
// Single-pass flash attention. One block per group; wave w owns keys
// [32w, 32w+32) and maintains online-softmax state for ALL 4 queries.
// No barriers in the streaming loop; k-prefetch + v-loads interleave.
// Final cross-wave combine per query through LDS.
// ---------------------------------------------------------------------------
__global__ __launch_bounds__(256, 4) void attn_kernel(
    const float* __restrict__ q, const float* __restrict__ k,
    const float* __restrict__ v, const int* __restrict__ m,
    const float* __restrict__ Mmat, const float* __restrict__ rvec,
    float* __restrict__ out)
{
    const int g    = blockIdx.x;
    const int t    = threadIdx.x;
    const int lane = t & 63;
    const int w    = t >> 6;

    __shared__ float  q_s[4][D];          //  4 KB
    __shared__ float4 part_s[4][4][64];   // 16 KB  (phase-1 partials, then acc partials)
    __shared__ float4 u_s4[4][64];        //  4 KB
    __shared__ float  tile_s[4][8][4];    //  0.5 KB per-wave e broadcast
    __shared__ float  su_s[4][4];
    __shared__ float  mm_s[4][4];

    // ---- stage q ----
    {
        const float4* qg = (const float4*)(q + (size_t)g * 4 * D);
        ((float4*)q_s)[t] = qg[t];
    }
    __syncthreads();

    // ---- phase 1a: u partials; wave w covers contraction dims [w*64, w*64+64) ----
    {
        const float4* M4 = (const float4*)Mmat;
        float4 p0 = {0,0,0,0}, p1 = {0,0,0,0}, p2 = {0,0,0,0}, p3 = {0,0,0,0};
        const int base = w * 64;
        #pragma unroll 4
        for (int dd = 0; dd < 64; ++dd) {
            const int a = base + dd;
            const float4 m4 = M4[a * 64 + lane];
            const float q0 = q_s[0][a], q1 = q_s[1][a], q2 = q_s[2][a], q3 = q_s[3][a];
            p0.x += q0*m4.x; p0.y += q0*m4.y; p0.z += q0*m4.z; p0.w += q0*m4.w;
            p1.x += q1*m4.x; p1.y += q1*m4.y; p1.z += q1*m4.z; p1.w += q1*m4.w;
            p2.x += q2*m4.x; p2.y += q2*m4.y; p2.z += q2*m4.z; p2.w += q2*m4.w;
            p3.x += q3*m4.x; p3.y += q3*m4.y; p3.z += q3*m4.z; p3.w += q3*m4.w;
        }
        part_s[w][0][lane] = p0; part_s[w][1][lane] = p1;
        part_s[w][2][lane] = p2; part_s[w][3][lane] = p3;
    }
    __syncthreads();

    // ---- phase 1b: reduce partials; fold 1/sqrt(d_z) into u ----
    {
        float4 acc = ((const float4*)rvec)[lane];
        const float4 a0 = part_s[0][w][lane], a1 = part_s[1][w][lane];
        const float4 a2 = part_s[2][w][lane], a3 = part_s[3][w][lane];
        acc.x = (acc.x + a0.x + a1.x + a2.x + a3.x) * 0.0625f;
        acc.y = (acc.y + a0.y + a1.y + a2.y + a3.y) * 0.0625f;
        acc.z = (acc.z + a0.z + a1.z + a2.z + a3.z) * 0.0625f;
        acc.w = (acc.w + a0.w + a1.w + a2.w + a3.w) * 0.0625f;
        u_s4[w][lane] = acc;
    }
    __syncthreads();

    const float4 u0 = u_s4[0][lane], u1 = u_s4[1][lane];
    const float4 u2 = u_s4[2][lane], u3 = u_s4[3][lane];

    // ---- wave-uniform mask bitmap for this wave's 32 keys ----
    const int l0 = w * 32;
    const int mk = (lane < 32) ? m[(size_t)g * LKEYS + l0 + lane] : 0;
    const unsigned long long bal = __ballot(mk != 0);

    const float4* kg = (const float4*)(k + (size_t)g * LKEYS * D);
    const float4* vg = (const float4*)(v + (size_t)g * LKEYS * D);

    // register transpose + butterfly: full dot for query (lane&3),
    // result UNIFORM within each 16-lane group {lane&3 == const}
    auto reduce_qt = [&](float d0, float d1, float d2, float d3) -> float {
        float keepA = (lane & 1) ? d1 : d0;
        float sendA = (lane & 1) ? d0 : d1;
        keepA += __shfl_xor(sendA, 1);
        float keepB = (lane & 1) ? d3 : d2;
        float sendB = (lane & 1) ? d2 : d3;
        keepB += __shfl_xor(sendB, 1);
        float keep = (lane & 2) ? keepB : keepA;
        float send = (lane & 2) ? keepA : keepB;
        keep += __shfl_xor(send, 2);
        keep += __shfl_xor(keep, 4);
        keep += __shfl_xor(keep, 8);
        keep += __shfl_xor(keep, 16);
        keep += __shfl_xor(keep, 32);
        return keep;
    };

    float m0 = -1e30f, m1 = -1e30f, m2 = -1e30f, m3 = -1e30f;
    float m_own = -1e30f, su_own = 0.f;
    float4 acc0 = {0,0,0,0}, acc1 = {0,0,0,0}, acc2 = {0,0,0,0}, acc3 = {0,0,0,0};

    float4 ka[8];
    #pragma unroll
    for (int j = 0; j < 8; ++j) ka[j] = kg[(l0 + j) * 64 + lane];

    #pragma unroll
    for (int tile = 0; tile < 4; ++tile) {
        const int lt = l0 + tile * 8;

        // scores for 8 keys (consumes ka)
        float sc[8];
        #pragma unroll
        for (int j = 0; j < 8; ++j) {
            const float4 kv = ka[j];
            const float d0 = kv.x*u0.x + kv.y*u0.y + kv.z*u0.z + kv.w*u0.w;
            const float d1 = kv.x*u1.x + kv.y*u1.y + kv.z*u1.z + kv.w*u1.w;
            const float d2 = kv.x*u2.x + kv.y*u2.y + kv.z*u2.z + kv.w*u2.w;
            const float d3 = kv.x*u3.x + kv.y*u3.y + kv.z*u3.z + kv.w*u3.w;
            sc[j] = reduce_qt(d0, d1, d2, d3);
        }

        // prefetch next k tile (ka regs free) + this tile's v rows
        if (tile < 3) {
            #pragma unroll
            for (int j = 0; j < 8; ++j) ka[j] = kg[(lt + 8 + j) * 64 + lane];
        }
        float4 va[8];
        #pragma unroll
        for (int j = 0; j < 8; ++j) va[j] = vg[(lt + j) * 64 + lane];

        // mask (wave-uniform SGPR selects)
        #pragma unroll
        for (int j = 0; j < 8; ++j) {
            const bool vj = (bal >> (tile * 8 + j)) & 1ull;
            sc[j] = vj ? sc[j] : -1e30f;
        }

        // tile max: already uniform per 16-lane group; broadcast across groups
        float tmax = sc[0];
        #pragma unroll
        for (int j = 1; j < 8; ++j) tmax = fmaxf(tmax, sc[j]);
        const float b1 = __shfl_xor(tmax, 1);
        const float b2 = __shfl_xor(tmax, 2);
        const float b3 = __shfl_xor(tmax, 3);
        const int   g0 = lane & 3;
        const float t0 = (g0==0)?tmax:(g0==1)?b1:(g0==2)?b2:b3;
        const float t1 = (g0==1)?tmax:(g0==0)?b1:(g0==3)?b2:b3;
        const float t2 = (g0==2)?tmax:(g0==3)?b1:(g0==0)?b2:b3;
        const float t3 = (g0==3)?tmax:(g0==2)?b1:(g0==1)?b2:b3;

        // online rescale of all 4 query accumulators
        const float nm0 = fmaxf(m0, t0), nm1 = fmaxf(m1, t1);
        const float nm2 = fmaxf(m2, t2), nm3 = fmaxf(m3, t3);
        const float s0 = __expf(m0 - nm0), s1 = __expf(m1 - nm1);
        const float s2 = __expf(m2 - nm2), s3 = __expf(m3 - nm3);
        m0 = nm0; m1 = nm1; m2 = nm2; m3 = nm3;
        acc0.x *= s0; acc0.y *= s0; acc0.z *= s0; acc0.w *= s0;
        acc1.x *= s1; acc1.y *= s1; acc1.z *= s1; acc1.w *= s1;
        acc2.x *= s2; acc2.y *= s2; acc2.z *= s2; acc2.w *= s2;
        acc3.x *= s3; acc3.y *= s3; acc3.z *= s3; acc3.w *= s3;

        // e for own query (uniform in group); masked -> exactly 0
        const float nmo = fmaxf(m_own, tmax);
        const float so  = __expf(m_own - nmo);
        m_own = nmo;
        float e[8]; float esum = 0.f;
        #pragma unroll
        for (int j = 0; j < 8; ++j) {
            const bool vj = (bal >> (tile * 8 + j)) & 1ull;
            const float ee = vj ? __expf(sc[j] - m_own) : 0.f;
            e[j] = ee; esum += ee;
        }
        su_own = su_own * so + esum;

        // publish e[l][qi] via per-wave LDS (same-wave write/read, no barrier)
        if (lane < 4) {
            #pragma unroll
            for (int j = 0; j < 8; ++j) tile_s[w][j][lane] = e[j];
        }

        // v accumulation: e4 = {e[j][qi=0..3]} broadcast read
        #pragma unroll
        for (int j = 0; j < 8; ++j) {
            const float4 e4 = *(const float4*)&tile_s[w][j][0];
            const float4 vv = va[j];
            acc0.x += e4.x*vv.x; acc0.y += e4.x*vv.y; acc0.z += e4.x*vv.z; acc0.w += e4.x*vv.w;
            acc1.x += e4.y*vv.x; acc1.y += e4.y*vv.y; acc1.z += e4.y*vv.z; acc1.w += e4.y*vv.w;
            acc2.x += e4.z*vv.x; acc2.y += e4.z*vv.y; acc2.z += e4.z*vv.z; acc2.w += e4.z*vv.w;
            acc3.x += e4.w*vv.x; acc3.y += e4.w*vv.y; acc3.z += e4.w*vv.z; acc3.w += e4.w*vv.w;
        }
    }

    // ---- cross-wave combine ----
    part_s[w][0][lane] = acc0; part_s[w][1][lane] = acc1;
    part_s[w][2][lane] = acc2; part_s[w][3][lane] = acc3;
    if (lane < 4) su_s[w][lane] = su_own;     // lane == qi
    if (lane == 0) { mm_s[w][0] = m0; mm_s[w][1] = m1; mm_s[w][2] = m2; mm_s[w][3] = m3; }
    __syncthreads();

    {   // wave w finalizes query w
        const float mA = mm_s[0][w], mB = mm_s[1][w], mC = mm_s[2][w], mD = mm_s[3][w];
        const float Mx = fmaxf(fmaxf(mA, mB), fmaxf(mC, mD));
        const float fA = __expf(mA - Mx), fB = __expf(mB - Mx);
        const float fC = __expf(mC - Mx), fD = __expf(mD - Mx);
        const float S = fA*su_s[0][w] + fB*su_s[1][w] + fC*su_s[2][w] + fD*su_s[3][w];
        const float inv = 1.0f / S;
        const float4 pA = part_s[0][w][lane], pB = part_s[1][w][lane];
        const float4 pC = part_s[2][w][lane], pD = part_s[3][w][lane];
        float4 o;
        o.x = (fA*pA.x + fB*pB.x + fC*pC.x + fD*pD.x) * inv;
        o.y = (fA*pA.y + fB*pB.y + fC*pC.y + fD*pD.y) * inv;
        o.z = (fA*pA.z + fB*pB.z + fC*pC.z + fD*pD.z) * inv;
        o.w = (fA*pA.w + fB*pB.w + fC*pC.w + fD*pD.w) * inv;
        ((float4*)(out + ((size_t)g * 4 + w) * D))[lane] = o;
    }
}

extern "C" void kernel_launch(void* const* d_in, const int* in_sizes, int n_in,
                              void* d_out, int out_size, void* d_ws, size_t ws_size,
                              hipStream_t stream) {
    // inputs: nq(0), q(1), k(2), v(3), m(4), Wq(5), bq(6), Wk(7), bk(8)
    const float* q  = (const float*)d_in[1];
    const float* k  = (const float*)d_in[2];
    const float* v  = (const float*)d_in[3];
    const int*   m  = (const int*)  d_in[4];
    const float* Wq = (const float*)d_in[5];
    const float* bq = (const float*)d_in[6];
    const float* Wk = (const float*)d_in[7];

    float* Mmat = (float*)d_ws;                // 256 KB
    float* rvec = Mmat + D * D;

    prep_kernel<<<64, 256, 0, stream>>>(Wq, Wk, bq, Mmat, rvec);
    attn_kernel<<<NGROUP, 256, 0, stream>>>(q, k, v, m, Mmat, rvec, (float*)d_out);
}

// Round 4
// 76.907 us; speedup vs baseline: 2.0711x; 2.0711x over previous
//
#include <hip/hip_runtime.h>

#define D 256
#define LKEYS 128
#define NGROUP 1024
#define NQ 4096

// ws layout (float offsets)
#define MMAT_OFF 0
#define RVEC_OFF (D * D)                    // 65536
#define U_OFF    (RVEC_OFF + D)             // 65792
#define PART_OFF (U_OFF + NQ * D)           // u: 4096x256
#define PART_STRIDE 260                     // acc[256], m, su, pad2
#define WS_FLOATS_SPLIT (PART_OFF + 2 * NQ * PART_STRIDE)   // ~13 MB

#define DOT4(a, b) ((a).x*(b).x + (a).y*(b).y + (a).z*(b).z + (a).w*(b).w)

// ---------------------------------------------------------------------------
// prep: M = Wq @ Wk^T, r = bq @ Wk^T. bk dropped (softmax-invariant).
// ---------------------------------------------------------------------------
__global__ __launch_bounds__(256) void prep_kernel(
    const float* __restrict__ Wq, const float* __restrict__ Wk,
    const float* __restrict__ bq, float* __restrict__ Mmat,
    float* __restrict__ rvec)
{
    __shared__ float wq_s[32][65];
    __shared__ float wk_s[32][65];
    __shared__ float bq_s[64];
    const int t  = threadIdx.x;
    const int a0 = (int)(blockIdx.x >> 3) * 32;
    const int b0 = (int)(blockIdx.x & 7) * 32;
    const int ai = t >> 4;
    const int bj = t & 15;
    float acc00 = 0.f, acc01 = 0.f, acc10 = 0.f, acc11 = 0.f;
    float racc = 0.f;
    for (int z0 = 0; z0 < D; z0 += 64) {
        __syncthreads();
        #pragma unroll
        for (int i = 0; i < 2; ++i) {
            const int f4i = t + 256 * i;
            const int row = f4i >> 4;
            const int c   = (f4i & 15) * 4;
            float4 aa = *(const float4*)&Wq[(size_t)(a0 + row) * D + z0 + c];
            wq_s[row][c] = aa.x; wq_s[row][c+1] = aa.y; wq_s[row][c+2] = aa.z; wq_s[row][c+3] = aa.w;
            float4 bb = *(const float4*)&Wk[(size_t)(b0 + row) * D + z0 + c];
            wk_s[row][c] = bb.x; wk_s[row][c+1] = bb.y; wk_s[row][c+2] = bb.z; wk_s[row][c+3] = bb.w;
        }
        if (t < 64) bq_s[t] = bq[z0 + t];
        __syncthreads();
        #pragma unroll 8
        for (int z = 0; z < 64; ++z) {
            const float wq0 = wq_s[ai][z];
            const float wq1 = wq_s[ai + 16][z];
            const float wk0 = wk_s[bj][z];
            const float wk1 = wk_s[bj + 16][z];
            acc00 += wq0 * wk0; acc01 += wq0 * wk1;
            acc10 += wq1 * wk0; acc11 += wq1 * wk1;
        }
        if (a0 == 0 && t < 32) {
            #pragma unroll 8
            for (int z = 0; z < 64; ++z) racc += bq_s[z] * wk_s[t][z];
        }
    }
    Mmat[(size_t)(a0 + ai)      * D + b0 + bj]      = acc00;
    Mmat[(size_t)(a0 + ai)      * D + b0 + bj + 16] = acc01;
    Mmat[(size_t)(a0 + ai + 16) * D + b0 + bj]      = acc10;
    Mmat[(size_t)(a0 + ai + 16) * D + b0 + bj + 16] = acc11;
    if (a0 == 0 && t < 32) rvec[b0 + t] = racc;
}

// ---------------------------------------------------------------------------
// u = (q @ M + r) * (1/sqrt(256)) for all 4096 queries. Block g: queries 4g..4g+3.
// ---------------------------------------------------------------------------
__global__ __launch_bounds__(256) void u_kernel(
    const float* __restrict__ q, const float* __restrict__ Mmat,
    const float* __restrict__ rvec, float* __restrict__ uout)
{
    __shared__ float  q_s[4][D];
    __shared__ float4 part_s[4][4][64];
    const int g = blockIdx.x, t = threadIdx.x, lane = t & 63, w = t >> 6;
    ((float4*)q_s)[t] = ((const float4*)(q + (size_t)g * 4 * D))[t];
    __syncthreads();
    {
        const float4* M4 = (const float4*)Mmat;
        float4 p0 = {0,0,0,0}, p1 = {0,0,0,0}, p2 = {0,0,0,0}, p3 = {0,0,0,0};
        const int base = w * 64;
        #pragma unroll 4
        for (int dd = 0; dd < 64; ++dd) {
            const int a = base + dd;
            const float4 m4 = M4[a * 64 + lane];
            const float q0 = q_s[0][a], q1 = q_s[1][a], q2 = q_s[2][a], q3 = q_s[3][a];
            p0.x += q0*m4.x; p0.y += q0*m4.y; p0.z += q0*m4.z; p0.w += q0*m4.w;
            p1.x += q1*m4.x; p1.y += q1*m4.y; p1.z += q1*m4.z; p1.w += q1*m4.w;
            p2.x += q2*m4.x; p2.y += q2*m4.y; p2.z += q2*m4.z; p2.w += q2*m4.w;
            p3.x += q3*m4.x; p3.y += q3*m4.y; p3.z += q3*m4.z; p3.w += q3*m4.w;
        }
        part_s[w][0][lane] = p0; part_s[w][1][lane] = p1;
        part_s[w][2][lane] = p2; part_s[w][3][lane] = p3;
    }
    __syncthreads();
    {
        float4 acc = ((const float4*)rvec)[lane];
        const float4 a0 = part_s[0][w][lane], a1 = part_s[1][w][lane];
        const float4 a2 = part_s[2][w][lane], a3 = part_s[3][w][lane];
        acc.x = (acc.x + a0.x + a1.x + a2.x + a3.x) * 0.0625f;
        acc.y = (acc.y + a0.y + a1.y + a2.y + a3.y) * 0.0625f;
        acc.z = (acc.z + a0.z + a1.z + a2.z + a3.z) * 0.0625f;
        acc.w = (acc.w + a0.w + a1.w + a2.w + a3.w) * 0.0625f;
        ((float4*)uout)[((size_t)g * 4 + w) * 64 + lane] = acc;
    }
}

// ---------------------------------------------------------------------------
// Split attention: block (g,h) handles group g, keys [64h, 64h+64).
// Wave w computes scores for keys [16w,16w+16) (all 4 queries) via batched
// tree-reduce (17 shuffles / 4 keys), then streams all 64 v rows for query w.
// Writes unnormalized partial (acc, m_loc, su) to ws.
// ---------------------------------------------------------------------------
__global__ __launch_bounds__(256, 4) void attn_split_kernel(
    const float* __restrict__ k, const float* __restrict__ v,
    const int* __restrict__ m, const float* __restrict__ uws,
    float* __restrict__ part)
{
    const int b = blockIdx.x;
    const int g = b >> 1, h = b & 1;
    const int t = threadIdx.x, lane = t & 63, w = t >> 6;
    __shared__ float p_s[4][64];

    const float4* U4 = (const float4*)uws;
    const float4 u0 = U4[((size_t)g * 4 + 0) * 64 + lane];
    const float4 u1 = U4[((size_t)g * 4 + 1) * 64 + lane];
    const float4 u2 = U4[((size_t)g * 4 + 2) * 64 + lane];
    const float4 u3 = U4[((size_t)g * 4 + 3) * 64 + lane];

    const int kofs = h * 64;
    const int mk = m[(size_t)g * LKEYS + kofs + lane];
    const unsigned long long bal = __ballot(mk != 0);

    const float4* kg = (const float4*)(k + ((size_t)g * LKEYS + kofs) * D);
    const float4* vg = (const float4*)(v + ((size_t)g * LKEYS + kofs) * D);

    // ---- scores: wave w keys [16w, 16w+16), batches of 4 ----
    #pragma unroll
    for (int it = 0; it < 4; ++it) {
        const int kb = w * 16 + it * 4;
        const float4 ka0 = kg[(kb + 0) * 64 + lane];
        const float4 ka1 = kg[(kb + 1) * 64 + lane];
        const float4 ka2 = kg[(kb + 2) * 64 + lane];
        const float4 ka3 = kg[(kb + 3) * 64 + lane];

        float v16[16];   // v16[key*4 + q]
        v16[ 0]=DOT4(ka0,u0); v16[ 1]=DOT4(ka0,u1); v16[ 2]=DOT4(ka0,u2); v16[ 3]=DOT4(ka0,u3);
        v16[ 4]=DOT4(ka1,u0); v16[ 5]=DOT4(ka1,u1); v16[ 6]=DOT4(ka1,u2); v16[ 7]=DOT4(ka1,u3);
        v16[ 8]=DOT4(ka2,u0); v16[ 9]=DOT4(ka2,u1); v16[10]=DOT4(ka2,u2); v16[11]=DOT4(ka2,u3);
        v16[12]=DOT4(ka3,u0); v16[13]=DOT4(ka3,u1); v16[14]=DOT4(ka3,u2); v16[15]=DOT4(ka3,u3);

        // tree reduce across 64 lanes: 16 -> 8 -> 4 -> 2 -> 1 values/lane
        float v8[8];
        {
            const int hb = lane & 1;
            #pragma unroll
            for (int i = 0; i < 8; ++i) {
                const float keep = hb ? v16[8 + i] : v16[i];
                const float send = hb ? v16[i]     : v16[8 + i];
                v8[i] = keep + __shfl_xor(send, 1);
            }
        }
        float v4a[4];
        {
            const int hb = (lane >> 1) & 1;
            #pragma unroll
            for (int i = 0; i < 4; ++i) {
                const float keep = hb ? v8[4 + i] : v8[i];
                const float send = hb ? v8[i]     : v8[4 + i];
                v4a[i] = keep + __shfl_xor(send, 2);
            }
        }
        float v2a[2];
        {
            const int hb = (lane >> 2) & 1;
            #pragma unroll
            for (int i = 0; i < 2; ++i) {
                const float keep = hb ? v2a[0]*0.f + v4a[2 + i] : v4a[i];
                const float send = hb ? v4a[i]     : v4a[2 + i];
                v2a[i] = keep + __shfl_xor(send, 4);
            }
        }
        float v1;
        {
            const int hb = (lane >> 3) & 1;
            const float keep = hb ? v2a[1] : v2a[0];
            const float send = hb ? v2a[0] : v2a[1];
            v1 = keep + __shfl_xor(send, 8);
        }
        v1 += __shfl_xor(v1, 16);
        v1 += __shfl_xor(v1, 32);

        if (lane < 16) {
            // lane bits b0..b3 -> value index i = b0*8 | b1*4 | b2*2 | b3
            const int i  = ((lane & 1) << 3) | ((lane & 2) << 1) | ((lane & 4) >> 1) | ((lane & 8) >> 3);
            const int kl = kb + (i >> 2);
            p_s[i & 3][kl] = ((bal >> kl) & 1ull) ? v1 : -1e30f;
        }
    }
    __syncthreads();

    // ---- softmax (unnormalized e, local max); wave w owns row w ----
    float m_loc, su;
    {
        const float s = p_s[w][lane];
        float mx = s;
        #pragma unroll
        for (int off = 32; off > 0; off >>= 1) mx = fmaxf(mx, __shfl_xor(mx, off));
        const bool valid = (bal >> lane) & 1ull;
        const float e = valid ? __expf(s - mx) : 0.f;   // all-masked half -> e=0, su=0
        float ss = e;
        #pragma unroll
        for (int off = 32; off > 0; off >>= 1) ss += __shfl_xor(ss, off);
        p_s[w][lane] = e;   // same-wave write/read
        m_loc = mx; su = ss;
    }

    // ---- v accumulation: wave w streams all 64 rows for query w ----
    float4 acc = {0, 0, 0, 0};
    for (int l = 0; l < 64; l += 8) {
        float4 va[8];
        #pragma unroll
        for (int j = 0; j < 8; ++j) va[j] = vg[(l + j) * 64 + lane];
        const float4 ea = *(const float4*)&p_s[w][l];
        const float4 eb = *(const float4*)&p_s[w][l + 4];
        acc.x += ea.x*va[0].x; acc.y += ea.x*va[0].y; acc.z += ea.x*va[0].z; acc.w += ea.x*va[0].w;
        acc.x += ea.y*va[1].x; acc.y += ea.y*va[1].y; acc.z += ea.y*va[1].z; acc.w += ea.y*va[1].w;
        acc.x += ea.z*va[2].x; acc.y += ea.z*va[2].y; acc.z += ea.z*va[2].z; acc.w += ea.z*va[2].w;
        acc.x += ea.w*va[3].x; acc.y += ea.w*va[3].y; acc.z += ea.w*va[3].z; acc.w += ea.w*va[3].w;
        acc.x += eb.x*va[4].x; acc.y += eb.x*va[4].y; acc.z += eb.x*va[4].z; acc.w += eb.x*va[4].w;
        acc.x += eb.y*va[5].x; acc.y += eb.y*va[5].y; acc.z += eb.y*va[5].z; acc.w += eb.y*va[5].w;
        acc.x += eb.z*va[6].x; acc.y += eb.z*va[6].y; acc.z += eb.z*va[6].z; acc.w += eb.z*va[6].w;
        acc.x += eb.w*va[7].x; acc.y += eb.w*va[7].y; acc.z += eb.w*va[7].z; acc.w += eb.w*va[7].w;
    }

    float* pb = part + ((size_t)h * NQ + (size_t)g * 4 + w) * PART_STRIDE;
    ((float4*)pb)[lane] = acc;
    if (lane == 0) { pb[256] = m_loc; pb[257] = su; }
}

// ---------------------------------------------------------------------------
// combine: out[i] = (fA*accA + fB*accB) / (fA*suA + fB*suB)
// ---------------------------------------------------------------------------
__global__ __launch_bounds__(256) void combine_kernel(
    const float* __restrict__ part, float* __restrict__ out)
{
    const int b = blockIdx.x, t = threadIdx.x, lane = t & 63, w = t >> 6;
    const int i = b * 4 + w;
    const float* pA = part + (size_t)i * PART_STRIDE;
    const float* pB = part + ((size_t)NQ + i) * PART_STRIDE;
    const float mA = pA[256], suA = pA[257];
    const float mB = pB[256], suB = pB[257];
    const float Mx = fmaxf(mA, mB);
    const float fA = __expf(mA - Mx);      // all-masked half: exp(-huge)=0
    const float fB = __expf(mB - Mx);
    const float inv = 1.0f / (fA * suA + fB * suB);
    const float4 aA = ((const float4*)pA)[lane];
    const float4 aB = ((const float4*)pB)[lane];
    float4 o;
    o.x = (fA*aA.x + fB*aB.x) * inv;
    o.y = (fA*aA.y + fB*aB.y) * inv;
    o.z = (fA*aA.z + fB*aB.z) * inv;
    o.w = (fA*aA.w + fB*aB.w) * inv;
    ((float4*)out)[(size_t)i * 64 + lane] = o;
}

// ---------------------------------------------------------------------------
// Fallback (ws too small for split path): proven R2 kernel.
// ---------------------------------------------------------------------------
__global__ __launch_bounds__(256) void attn_kernel(
    const float* __restrict__ q, const float* __restrict__ k,
    const float* __restrict__ v, const int* __restrict__ m,
    const float* __restrict__ Mmat, const float* __restrict__ rvec,
    float* __restrict__ out)
{
    const int g    = blockIdx.x;
    const int t    = threadIdx.x;
    const int lane = t & 63;
    const int w    = t >> 6;

    __shared__ float  q_s[4][D];
    __shared__ float4 part_s[4][4][64];
    __shared__ float4 u_s4[4][64];
    __shared__ float  p_s[4][LKEYS];
    __shared__ int    m_s[LKEYS];

    {
        const float4* qg = (const float4*)(q + (size_t)g * 4 * D);
        ((float4*)q_s)[t] = qg[t];
    }
    if (t < LKEYS) m_s[t] = m[(size_t)g * LKEYS + t];
    __syncthreads();
    {
        const float4* M4 = (const float4*)Mmat;
        float4 p0 = {0,0,0,0}, p1 = {0,0,0,0}, p2 = {0,0,0,0}, p3 = {0,0,0,0};
        const int base = w * 64;
        #pragma unroll 4
        for (int dd = 0; dd < 64; ++dd) {
            const int a = base + dd;
            const float4 m4 = M4[a * 64 + lane];
            const float q0 = q_s[0][a], q1 = q_s[1][a], q2 = q_s[2][a], q3 = q_s[3][a];
            p0.x += q0*m4.x; p0.y += q0*m4.y; p0.z += q0*m4.z; p0.w += q0*m4.w;
            p1.x += q1*m4.x; p1.y += q1*m4.y; p1.z += q1*m4.z; p1.w += q1*m4.w;
            p2.x += q2*m4.x; p2.y += q2*m4.y; p2.z += q2*m4.z; p2.w += q2*m4.w;
            p3.x += q3*m4.x; p3.y += q3*m4.y; p3.z += q3*m4.z; p3.w += q3*m4.w;
        }
        part_s[w][0][lane] = p0; part_s[w][1][lane] = p1;
        part_s[w][2][lane] = p2; part_s[w][3][lane] = p3;
    }
    __syncthreads();
    {
        float4 acc = ((const float4*)rvec)[lane];
        const float4 a0 = part_s[0][w][lane], a1 = part_s[1][w][lane];
        const float4 a2 = part_s[2][w][lane], a3 = part_s[3][w][lane];
        acc.x += a0.x + a1.x + a2.x + a3.x;
        acc.y += a0.y + a1.y + a2.y + a3.y;
        acc.z += a0.z + a1.z + a2.z + a3.z;
        acc.w += a0.w + a1.w + a2.w + a3.w;
        u_s4[w][lane] = acc;
    }
    __syncthreads();

    const float4 u0 = u_s4[0][lane], u1 = u_s4[1][lane];
    const float4 u2 = u_s4[2][lane], u3 = u_s4[3][lane];
    {
        const float4* kg = (const float4*)(k + (size_t)g * LKEYS * D);
        auto reduce_qt = [&](float d0, float d1, float d2, float d3) -> float {
            float keepA = (lane & 1) ? d1 : d0;
            float sendA = (lane & 1) ? d0 : d1;
            keepA += __shfl_xor(sendA, 1);
            float keepB = (lane & 1) ? d3 : d2;
            float sendB = (lane & 1) ? d2 : d3;
            keepB += __shfl_xor(sendB, 1);
            float keep = (lane & 2) ? keepB : keepA;
            float send = (lane & 2) ? keepA : keepB;
            keep += __shfl_xor(send, 2);
            keep += __shfl_xor(keep, 4);
            keep += __shfl_xor(keep, 8);
            keep += __shfl_xor(keep, 16);
            keep += __shfl_xor(keep, 32);
            return keep;
        };
        const int l0 = w * 32;
        for (int kk = 0; kk < 32; kk += 4) {
            const int l = l0 + kk;
            const float4 kA = kg[(l + 0) * 64 + lane];
            const float4 kB = kg[(l + 1) * 64 + lane];
            const float4 kC = kg[(l + 2) * 64 + lane];
            const float4 kD = kg[(l + 3) * 64 + lane];
            float dA0 = DOT4(kA,u0), dA1 = DOT4(kA,u1), dA2 = DOT4(kA,u2), dA3 = DOT4(kA,u3);
            float dB0 = DOT4(kB,u0), dB1 = DOT4(kB,u1), dB2 = DOT4(kB,u2), dB3 = DOT4(kB,u3);
            float dC0 = DOT4(kC,u0), dC1 = DOT4(kC,u1), dC2 = DOT4(kC,u2), dC3 = DOT4(kC,u3);
            float dD0 = DOT4(kD,u0), dD1 = DOT4(kD,u1), dD2 = DOT4(kD,u2), dD3 = DOT4(kD,u3);
            const float rA = reduce_qt(dA0, dA1, dA2, dA3);
            const float rB = reduce_qt(dB0, dB1, dB2, dB3);
            const float rC = reduce_qt(dC0, dC1, dC2, dC3);
            const float rD = reduce_qt(dD0, dD1, dD2, dD3);
            if (lane < 4) {
                p_s[lane][l + 0] = m_s[l + 0] ? rA * 0.0625f : -1e30f;
                p_s[lane][l + 1] = m_s[l + 1] ? rB * 0.0625f : -1e30f;
                p_s[lane][l + 2] = m_s[l + 2] ? rC * 0.0625f : -1e30f;
                p_s[lane][l + 3] = m_s[l + 3] ? rD * 0.0625f : -1e30f;
            }
        }
    }
    __syncthreads();
    {
        const float v0 = p_s[w][lane];
        const float v1 = p_s[w][lane + 64];
        float mx = fmaxf(v0, v1);
        #pragma unroll
        for (int off = 32; off > 0; off >>= 1) mx = fmaxf(mx, __shfl_xor(mx, off));
        const float e0 = __expf(v0 - mx);
        const float e1 = __expf(v1 - mx);
        float sm = e0 + e1;
        #pragma unroll
        for (int off = 32; off > 0; off >>= 1) sm += __shfl_xor(sm, off);
        const float inv = 1.0f / sm;
        p_s[w][lane]      = e0 * inv;
        p_s[w][lane + 64] = e1 * inv;
    }
    {
        const float4* vg = (const float4*)(v + (size_t)g * LKEYS * D);
        float4 acc = {0,0,0,0};
        #pragma unroll 8
        for (int l = 0; l < LKEYS; ++l) {
            const float pw = p_s[w][l];
            const float4 vv = vg[l * 64 + lane];
            acc.x += pw * vv.x; acc.y += pw * vv.y;
            acc.z += pw * vv.z; acc.w += pw * vv.w;
        }
        float4* og = (float4*)(out + ((size_t)g * 4 + w) * D);
        og[lane] = acc;
    }
}

extern "C" void kernel_launch(void* const* d_in, const int* in_sizes, int n_in,
                              void* d_out, int out_size, void* d_ws, size_t ws_size,
                              hipStream_t stream) {
    // inputs: nq(0), q(1), k(2), v(3), m(4), Wq(5), bq(6), Wk(7), bk(8)
    const float* q  = (const float*)d_in[1];
    const float* k  = (const float*)d_in[2];
    const float* v  = (const float*)d_in[3];
    const int*   m  = (const int*)  d_in[4];
    const float* Wq = (const float*)d_in[5];
    const float* bq = (const float*)d_in[6];
    const float* Wk = (const float*)d_in[7];

    float* ws = (float*)d_ws;
    prep_kernel<<<64, 256, 0, stream>>>(Wq, Wk, bq, ws + MMAT_OFF, ws + RVEC_OFF);

    if (ws_size >= (size_t)WS_FLOATS_SPLIT * sizeof(float)) {
        u_kernel<<<NGROUP, 256, 0, stream>>>(q, ws + MMAT_OFF, ws + RVEC_OFF, ws + U_OFF);
        attn_split_kernel<<<NGROUP * 2, 256, 0, stream>>>(k, v, m, ws + U_OFF, ws + PART_OFF);
        combine_kernel<<<NGROUP, 256, 0, stream>>>(ws + PART_OFF, (float*)d_out);
    } else {
        attn_kernel<<<NGROUP, 256, 0, stream>>>(q, k, v, m, ws + MMAT_OFF, ws + RVEC_OFF,
                                                (float*)d_out);
    }
}